// Round 4
// baseline (673.771 us; speedup 1.0000x reference)
//
#include <hip/hip_runtime.h>
#include <math.h>

// Shape: B=2 C=8 N=16384 D=256 H=W=64 ; rows = B*N = 32768
#define NROWS 32768

typedef __attribute__((ext_vector_type(8))) short short8;
typedef __attribute__((ext_vector_type(4))) float f32x4;

// Workspace layout (units of float):
//  ABF    ushort[256*256]  A^T in bf16:   Abf[e*256+f] = bf16(sum_d Wq[f,d]*Wk[e,d])
//  WVOBF  ushort[256*256]  Wvo^T in bf16: Wvobf[d*256+e] = bf16(sum_g Wv[e,g]*Wo[g,d])
//  PB     float[256]       bq @ Wk^T  (pre-scaled by 1/16)
//  BVO    float[256]       bv @ Wo
//  FEATBF ushort[2*8*64*64*256]  bf16 copy of image_features
// total = 66048 + 8388608 floats = 33.8 MB (was 67.5 MB)
#define WS_ABF    0
#define WS_WVOBF  32768
#define WS_PB     65536
#define WS_BVO    65792
#define WS_FEATBF 66048

__device__ __forceinline__ unsigned short f2bf(float f) {
    unsigned u = __builtin_bit_cast(unsigned, f);
    u += 0x7FFFu + ((u >> 16) & 1u);          // RNE
    return (unsigned short)(u >> 16);
}
__device__ __forceinline__ float bf_lo(unsigned u) {
    return __builtin_bit_cast(float, u << 16);
}
__device__ __forceinline__ float bf_hi(unsigned u) {
    return __builtin_bit_cast(float, u & 0xFFFF0000u);
}

// ---------------- precompute: A^T(bf16), Wvo^T(bf16), pb, bvo, feat->bf16 -------------
// feat conversion: 4096 blocks, 16 floats (64 B) per thread -> streaming-efficient.
__global__ __launch_bounds__(256)
void precompute_kernel(const float* __restrict__ Wq, const float* __restrict__ bq,
                       const float* __restrict__ Wkv, const float* __restrict__ bkv,
                       const float* __restrict__ Wo, const float* __restrict__ feat,
                       float* __restrict__ ws) {
    int t = threadIdx.x;
    int blk = blockIdx.x;
    if (blk >= 514) {
        // feature map fp32 -> bf16, 4096 floats per block, 16 per thread
        long i = (long)(blk - 514) * 4096 + t * 16;
        const float4* src = (const float4*)(feat + i);
        unsigned short* dst = (unsigned short*)(ws + WS_FEATBF) + i;
        #pragma unroll
        for (int h = 0; h < 2; ++h) {
            float4 a = src[2 * h], b = src[2 * h + 1];
            uint4 o;
            o.x = (unsigned)f2bf(a.x) | ((unsigned)f2bf(a.y) << 16);
            o.y = (unsigned)f2bf(a.z) | ((unsigned)f2bf(a.w) << 16);
            o.z = (unsigned)f2bf(b.x) | ((unsigned)f2bf(b.y) << 16);
            o.w = (unsigned)f2bf(b.z) | ((unsigned)f2bf(b.w) << 16);
            *(uint4*)(dst + 8 * h) = o;
        }
        return;
    }
    if (blk < 256) {
        // Abf[e][f] = bf16( Wq[f,:] . Wk[e,:] ),  f = blk, e = t
        int f = blk;
        const float4* wq4 = (const float4*)(Wq + f * 256);
        const float4* wk4 = (const float4*)(Wkv + (long)t * 512);
        float acc = 0.f;
        #pragma unroll 8
        for (int d4 = 0; d4 < 64; ++d4) {
            float4 a = wq4[d4], b = wk4[d4];
            acc += a.x * b.x + a.y * b.y + a.z * b.z + a.w * b.w;
        }
        ((unsigned short*)(ws + WS_ABF))[t * 256 + f] = f2bf(acc);
    } else if (blk < 512) {
        // Wvobf[d][e] = bf16( sum_g Wkv[e,256+g] * Wo[g,d] ),  e = blk-256, d = t
        int e = blk - 256;
        float acc = 0.f;
        #pragma unroll 8
        for (int g = 0; g < 256; ++g)
            acc = fmaf(Wkv[(long)e * 512 + 256 + g], Wo[g * 256 + t], acc);
        ((unsigned short*)(ws + WS_WVOBF))[t * 256 + e] = f2bf(acc);
    } else if (blk == 512) {
        float acc = 0.f;
        #pragma unroll 8
        for (int d = 0; d < 256; ++d)
            acc = fmaf(bq[d], Wkv[(long)t * 512 + d], acc);
        ws[WS_PB + t] = acc * 0.0625f;   // fold 1/sqrt(D) into p
    } else {
        float acc = 0.f;
        #pragma unroll 8
        for (int g = 0; g < 256; ++g)
            acc = fmaf(bkv[256 + g], Wo[g * 256 + t], acc);
        ws[WS_BVO + t] = acc;
    }
}

// ======================================================================================
// Fused row pipeline: LN -> p-GEMM -> sample/softmax -> out-GEMM -> store
// 32 rows per block, 8 waves (512 threads).
// GEMM phases: wave owns output cols [wave*32, wave*32+32), rows via mt in {0,1}.
// Phase 3: one row per 32-lane HALF-WAVE (lane covers 8 dims, uint4 gathers,
//          5-step butterfly, predicated online softmax).
// LDS 33.4 KB -> 4 blocks/CU x 8 waves = 32 waves/CU (100% occupancy cap).
// One LDS slab reused across phases:
//   phase1: qs bf16   (row r at buf + r*SLOT, first 512 B of slot); residual in regs
//   phase2: p/16 fp32 (row r at buf + r*SLOT, 1024 B)   [sync before overwrite]
//   phase3: sbar bf16 (overlays p row r — safe: sbar data-depends on p reads, same half)
//   phase4: out fp32  tile (after sync)
// ======================================================================================
#define RPB  32
#define SLOT 260   // floats per row slot (1040 B)

__global__ __launch_bounds__(512, 8)
void fused_rowpipe(const float* __restrict__ queries, const float* __restrict__ gamma,
                   const float* __restrict__ beta, const float* __restrict__ coords,
                   const int* __restrict__ vmask, const float* __restrict__ bo,
                   const float* __restrict__ ws, float* __restrict__ out) {
    __shared__ float buf[RPB * SLOT + RPB];
    float* ssu = buf + RPB * SLOT;

    const unsigned short* Abf    = (const unsigned short*)(ws + WS_ABF);
    const unsigned short* Wvobf  = (const unsigned short*)(ws + WS_WVOBF);
    const float*          pb     = ws + WS_PB;
    const float*          bvo    = ws + WS_BVO;
    const unsigned short* featbf = (const unsigned short*)(ws + WS_FEATBF);

    int tid = threadIdx.x, wave = tid >> 6, lane = tid & 63;
    long row0 = (long)blockIdx.x * RPB;

    float4 qstash[4];   // residual rows for phase 5 (same addresses as phase 1 loads)

    // ---------------- phase 1: layernorm -> qs bf16 ----------------
    {
        float4 g4 = *(const float4*)(gamma + 4 * lane);
        float4 b4 = *(const float4*)(beta + 4 * lane);
        #pragma unroll
        for (int rr = 0; rr < 4; ++rr) {
            int r = wave * 4 + rr;
            float4 v = *(const float4*)(queries + (row0 + r) * 256 + 4 * lane);
            qstash[rr] = v;
            float s = v.x + v.y + v.z + v.w;
            s += __shfl_xor(s, 32); s += __shfl_xor(s, 16); s += __shfl_xor(s, 8);
            s += __shfl_xor(s, 4);  s += __shfl_xor(s, 2);  s += __shfl_xor(s, 1);
            float mu = s * 0.00390625f;
            float dx = v.x - mu, dy = v.y - mu, dz = v.z - mu, dw = v.w - mu;
            float vv = dx * dx + dy * dy + dz * dz + dw * dw;
            vv += __shfl_xor(vv, 32); vv += __shfl_xor(vv, 16); vv += __shfl_xor(vv, 8);
            vv += __shfl_xor(vv, 4);  vv += __shfl_xor(vv, 2);  vv += __shfl_xor(vv, 1);
            float rstd = rsqrtf(vv * 0.00390625f + 1e-5f);
            float qx = dx * rstd * g4.x + b4.x;
            float qy = dy * rstd * g4.y + b4.y;
            float qz = dz * rstd * g4.z + b4.z;
            float qw = dw * rstd * g4.w + b4.w;
            unsigned lo = (unsigned)f2bf(qx) | ((unsigned)f2bf(qy) << 16);
            unsigned hi = (unsigned)f2bf(qz) | ((unsigned)f2bf(qw) << 16);
            *(uint2*)((unsigned short*)&buf[r * SLOT] + 4 * lane) = make_uint2(lo, hi);
        }
    }
    __syncthreads();

    int r16 = lane & 15, g = lane >> 4;
    f32x4 zero = {0.f, 0.f, 0.f, 0.f};

    // ---------------- phase 2: p = (LN(q) @ A^T + pb)/16  (MFMA) ----------------
    {
        f32x4 acc[2][2];
        #pragma unroll
        for (int mt = 0; mt < 2; ++mt)
            #pragma unroll
            for (int nt = 0; nt < 2; ++nt) acc[mt][nt] = zero;

        #pragma unroll
        for (int ks = 0; ks < 8; ++ks) {
            short8 bfr[2], afr[2];
            #pragma unroll
            for (int nt = 0; nt < 2; ++nt)
                bfr[nt] = *(const short8*)(Abf + ((wave * 32 + nt * 16 + r16) << 8) + ks * 32 + g * 8);
            #pragma unroll
            for (int mt = 0; mt < 2; ++mt)
                afr[mt] = *(const short8*)((const unsigned short*)buf + (mt * 16 + r16) * (SLOT * 2) + ks * 32 + g * 8);
            #pragma unroll
            for (int mt = 0; mt < 2; ++mt)
                #pragma unroll
                for (int nt = 0; nt < 2; ++nt)
                    acc[mt][nt] = __builtin_amdgcn_mfma_f32_16x16x32_bf16(afr[mt], bfr[nt], acc[mt][nt], 0, 0, 0);
        }
        __syncthreads();   // all qs reads complete before overwriting slab with p

        float pbv[2];
        #pragma unroll
        for (int nt = 0; nt < 2; ++nt) pbv[nt] = pb[wave * 32 + nt * 16 + r16];
        #pragma unroll
        for (int mt = 0; mt < 2; ++mt)
            #pragma unroll
            for (int nt = 0; nt < 2; ++nt)
                #pragma unroll
                for (int rg = 0; rg < 4; ++rg)
                    buf[(mt * 16 + g * 4 + rg) * SLOT + wave * 32 + nt * 16 + r16] =
                        acc[mt][nt][rg] * 0.0625f + pbv[nt];
    }
    __syncthreads();

    // ---------------- phase 3: sample + score + online softmax (half-wave/row) --------
    {
        int half = lane >> 5, l5 = lane & 31;
        #pragma unroll
        for (int it = 0; it < 2; ++it) {
            int r = wave * 4 + it * 2 + half;
            long rowl = row0 + r;
            int b = (int)(rowl >> 14);
            int n = (int)(rowl & 16383);

            float4 pA = *(const float4*)(&buf[r * SLOT + 8 * l5]);
            float4 pB = *(const float4*)(&buf[r * SLOT + 8 * l5 + 4]);

            float m = -INFINITY, ssum = 0.f;
            float4 sA = {0.f, 0.f, 0.f, 0.f}, sB = {0.f, 0.f, 0.f, 0.f};

            #pragma unroll
            for (int c = 0; c < 8; ++c) {
                long cb = (long)(b * 8 + c) * 16384 + n;
                float cx = coords[2 * cb];
                float cy = coords[2 * cb + 1];
                bool vld = (vmask[cb] != 0);
                float x = (cx + 1.f) * 31.5f;
                float y = (cy + 1.f) * 31.5f;
                float x0f = floorf(x), y0f = floorf(y);
                float wx = x - x0f, wy = y - y0f;
                int ix0 = (int)x0f, iy0 = (int)y0f;
                int ix1 = ix0 + 1, iy1 = iy0 + 1;
                float bx0 = (ix0 >= 0 && ix0 < 64) ? 1.f : 0.f;
                float bx1 = (ix1 >= 0 && ix1 < 64) ? 1.f : 0.f;
                float by0 = (iy0 >= 0 && iy0 < 64) ? 1.f : 0.f;
                float by1 = (iy1 >= 0 && iy1 < 64) ? 1.f : 0.f;
                int cx0 = min(max(ix0, 0), 63), cx1 = min(max(ix1, 0), 63);
                int cy0 = min(max(iy0, 0), 63), cy1 = min(max(iy1, 0), 63);
                const unsigned short* fb = featbf + ((long)(b * 8 + c) << 20);
                uint4 v00 = *((const uint4*)(fb + ((cy0 * 64 + cx0) << 8)) + l5);
                uint4 v01 = *((const uint4*)(fb + ((cy0 * 64 + cx1) << 8)) + l5);
                uint4 v10 = *((const uint4*)(fb + ((cy1 * 64 + cx0) << 8)) + l5);
                uint4 v11 = *((const uint4*)(fb + ((cy1 * 64 + cx1) << 8)) + l5);
                float w00 = (1.f - wy) * (1.f - wx) * by0 * bx0;
                float w01 = (1.f - wy) * wx * by0 * bx1;
                float w10 = wy * (1.f - wx) * by1 * bx0;
                float w11 = wy * wx * by1 * bx1;
                float s0 = w00*bf_lo(v00.x) + w01*bf_lo(v01.x) + w10*bf_lo(v10.x) + w11*bf_lo(v11.x);
                float s1 = w00*bf_hi(v00.x) + w01*bf_hi(v01.x) + w10*bf_hi(v10.x) + w11*bf_hi(v11.x);
                float s2 = w00*bf_lo(v00.y) + w01*bf_lo(v01.y) + w10*bf_lo(v10.y) + w11*bf_lo(v11.y);
                float s3 = w00*bf_hi(v00.y) + w01*bf_hi(v01.y) + w10*bf_hi(v10.y) + w11*bf_hi(v11.y);
                float s4 = w00*bf_lo(v00.z) + w01*bf_lo(v01.z) + w10*bf_lo(v10.z) + w11*bf_lo(v11.z);
                float s5 = w00*bf_hi(v00.z) + w01*bf_hi(v01.z) + w10*bf_hi(v10.z) + w11*bf_hi(v11.z);
                float s6 = w00*bf_lo(v00.w) + w01*bf_lo(v01.w) + w10*bf_lo(v10.w) + w11*bf_lo(v11.w);
                float s7 = w00*bf_hi(v00.w) + w01*bf_hi(v01.w) + w10*bf_hi(v10.w) + w11*bf_hi(v11.w);
                float t = s0 * pA.x + s1 * pA.y + s2 * pA.z + s3 * pA.w
                        + s4 * pB.x + s5 * pB.y + s6 * pB.z + s7 * pB.w;
                t += __shfl_xor(t, 16); t += __shfl_xor(t, 8); t += __shfl_xor(t, 4);
                t += __shfl_xor(t, 2);  t += __shfl_xor(t, 1);
                // predicated online softmax (NaN-guarded; 1/16 folded into p)
                float nm = vld ? fmaxf(m, t) : m;
                float d  = (m > -INFINITY) ? (m - nm) : 0.f;
                float scale = __expf(d);
                float w = vld ? __expf(t - nm) : 0.f;
                ssum = ssum * scale + w;
                sA.x = fmaf(w, s0, sA.x * scale);
                sA.y = fmaf(w, s1, sA.y * scale);
                sA.z = fmaf(w, s2, sA.z * scale);
                sA.w = fmaf(w, s3, sA.w * scale);
                sB.x = fmaf(w, s4, sB.x * scale);
                sB.y = fmaf(w, s5, sB.y * scale);
                sB.z = fmaf(w, s6, sB.z * scale);
                sB.w = fmaf(w, s7, sB.w * scale);
                m = nm;
            }

            float inv = (m > -INFINITY) ? (1.f / ssum) : 0.f;
            float sa  = (m > -INFINITY) ? 1.f : 0.f;
            // sbar bf16 overlays this row's p storage (data-depends on p reads, same half)
            uint4 o;
            o.x = (unsigned)f2bf(sA.x * inv) | ((unsigned)f2bf(sA.y * inv) << 16);
            o.y = (unsigned)f2bf(sA.z * inv) | ((unsigned)f2bf(sA.w * inv) << 16);
            o.z = (unsigned)f2bf(sB.x * inv) | ((unsigned)f2bf(sB.y * inv) << 16);
            o.w = (unsigned)f2bf(sB.z * inv) | ((unsigned)f2bf(sB.w * inv) << 16);
            *(uint4*)((unsigned short*)&buf[r * SLOT] + 8 * l5) = o;
            if (l5 == 0) ssu[r] = sa;
        }
    }
    __syncthreads();

    // ---------------- phase 4: out-GEMM: sbar @ Wvo^T  (MFMA) ----------------
    {
        f32x4 acc2[2][2];
        #pragma unroll
        for (int mt = 0; mt < 2; ++mt)
            #pragma unroll
            for (int nt = 0; nt < 2; ++nt) acc2[mt][nt] = zero;

        #pragma unroll
        for (int ks = 0; ks < 8; ++ks) {
            short8 bfr[2], afr[2];
            #pragma unroll
            for (int nt = 0; nt < 2; ++nt)
                bfr[nt] = *(const short8*)(Wvobf + ((wave * 32 + nt * 16 + r16) << 8) + ks * 32 + g * 8);
            #pragma unroll
            for (int mt = 0; mt < 2; ++mt)
                afr[mt] = *(const short8*)((const unsigned short*)buf + (mt * 16 + r16) * (SLOT * 2) + ks * 32 + g * 8);
            #pragma unroll
            for (int mt = 0; mt < 2; ++mt)
                #pragma unroll
                for (int nt = 0; nt < 2; ++nt)
                    acc2[mt][nt] = __builtin_amdgcn_mfma_f32_16x16x32_bf16(afr[mt], bfr[nt], acc2[mt][nt], 0, 0, 0);
        }
        __syncthreads();   // all sbar reads complete before overwriting slab with out tile

        #pragma unroll
        for (int mt = 0; mt < 2; ++mt)
            #pragma unroll
            for (int nt = 0; nt < 2; ++nt)
                #pragma unroll
                for (int rg = 0; rg < 4; ++rg)
                    buf[(mt * 16 + g * 4 + rg) * SLOT + wave * 32 + nt * 16 + r16] = acc2[mt][nt][rg];
    }
    __syncthreads();

    // ---------------- phase 5: out = residual + tile + suma*bvo + bo  (float4 stores) --
    {
        float4 bvo4 = *(const float4*)(bvo + 4 * lane);
        float4 bo4  = *(const float4*)(bo + 4 * lane);
        #pragma unroll
        for (int rr = 0; rr < 4; ++rr) {
            int r = wave * 4 + rr;
            float4 q4 = qstash[rr];
            float4 a4 = *(const float4*)(&buf[r * SLOT + 4 * lane]);
            float su = ssu[r];
            float4 o;
            o.x = q4.x + a4.x + su * bvo4.x + bo4.x;
            o.y = q4.y + a4.y + su * bvo4.y + bo4.y;
            o.z = q4.z + a4.z + su * bvo4.z + bo4.z;
            o.w = q4.w + a4.w + su * bvo4.w + bo4.w;
            *(float4*)(out + (row0 + r) * 256 + 4 * lane) = o;
        }
    }
}

extern "C" void kernel_launch(void* const* d_in, const int* in_sizes, int n_in,
                              void* d_out, int out_size, void* d_ws, size_t ws_size,
                              hipStream_t stream) {
    const float* queries = (const float*)d_in[0];
    const float* feat    = (const float*)d_in[1];
    const float* coords  = (const float*)d_in[2];
    const int*   vmask   = (const int*)  d_in[3];
    const float* Wq      = (const float*)d_in[4];
    const float* bq      = (const float*)d_in[5];
    const float* Wkv     = (const float*)d_in[6];
    const float* bkv     = (const float*)d_in[7];
    const float* Wo      = (const float*)d_in[8];
    const float* bo      = (const float*)d_in[9];
    const float* gamma   = (const float*)d_in[10];
    const float* beta    = (const float*)d_in[11];
    float* out = (float*)d_out;
    float* ws  = (float*)d_ws;

    precompute_kernel<<<514 + 4096, 256, 0, stream>>>(Wq, bq, Wkv, bkv, Wo, feat, ws);
    fused_rowpipe<<<NROWS / RPB, 512, 0, stream>>>(queries, gamma, beta, coords, vmask, bo, ws, out);
}

// Round 5
// 278.469 us; speedup vs baseline: 2.4196x; 2.4196x over previous
//
#include <hip/hip_runtime.h>
#include <math.h>

// Shape: B=2 C=8 N=16384 D=256 H=W=64 ; rows = B*N = 32768
#define NROWS 32768

typedef __attribute__((ext_vector_type(8))) short short8;
typedef __attribute__((ext_vector_type(4))) float f32x4;

// Workspace layout (units of float):
//  ABF    ushort[256*256]  A^T in bf16:   Abf[e*256+f] = bf16(sum_d Wq[f,d]*Wk[e,d])
//  WVOBF  ushort[256*256]  Wvo^T in bf16: Wvobf[d*256+e] = bf16(sum_g Wv[e,g]*Wo[g,d])
//  PB     float[256]       bq @ Wk^T  (pre-scaled by 1/16)
//  BVO    float[256]       bv @ Wo
//  FEATBF ushort[2*8*64*64*256]  bf16 copy of image_features
#define WS_ABF    0
#define WS_WVOBF  32768
#define WS_PB     65536
#define WS_BVO    65792
#define WS_FEATBF 66048

__device__ __forceinline__ unsigned short f2bf(float f) {
    unsigned u = __builtin_bit_cast(unsigned, f);
    u += 0x7FFFu + ((u >> 16) & 1u);          // RNE
    return (unsigned short)(u >> 16);
}
__device__ __forceinline__ float bf_lo(unsigned u) {
    return __builtin_bit_cast(float, u << 16);
}
__device__ __forceinline__ float bf_hi(unsigned u) {
    return __builtin_bit_cast(float, u & 0xFFFF0000u);
}

// ---------------- precompute: A^T(bf16), Wvo^T(bf16), pb, bvo, feat->bf16 -------------
__global__ __launch_bounds__(256)
void precompute_kernel(const float* __restrict__ Wq, const float* __restrict__ bq,
                       const float* __restrict__ Wkv, const float* __restrict__ bkv,
                       const float* __restrict__ Wo, const float* __restrict__ feat,
                       float* __restrict__ ws) {
    int t = threadIdx.x;
    int blk = blockIdx.x;
    if (blk >= 514) {
        // feature map fp32 -> bf16, 4096 floats per block, 16 per thread
        long i = (long)(blk - 514) * 4096 + t * 16;
        const float4* src = (const float4*)(feat + i);
        unsigned short* dst = (unsigned short*)(ws + WS_FEATBF) + i;
        #pragma unroll
        for (int h = 0; h < 2; ++h) {
            float4 a = src[2 * h], b = src[2 * h + 1];
            uint4 o;
            o.x = (unsigned)f2bf(a.x) | ((unsigned)f2bf(a.y) << 16);
            o.y = (unsigned)f2bf(a.z) | ((unsigned)f2bf(a.w) << 16);
            o.z = (unsigned)f2bf(b.x) | ((unsigned)f2bf(b.y) << 16);
            o.w = (unsigned)f2bf(b.z) | ((unsigned)f2bf(b.w) << 16);
            *(uint4*)(dst + 8 * h) = o;
        }
        return;
    }
    if (blk < 256) {
        // Abf[e][f] = bf16( Wq[f,:] . Wk[e,:] ),  f = blk, e = t
        int f = blk;
        const float4* wq4 = (const float4*)(Wq + f * 256);
        const float4* wk4 = (const float4*)(Wkv + (long)t * 512);
        float acc = 0.f;
        #pragma unroll 8
        for (int d4 = 0; d4 < 64; ++d4) {
            float4 a = wq4[d4], b = wk4[d4];
            acc += a.x * b.x + a.y * b.y + a.z * b.z + a.w * b.w;
        }
        ((unsigned short*)(ws + WS_ABF))[t * 256 + f] = f2bf(acc);
    } else if (blk < 512) {
        // Wvobf[d][e] = bf16( sum_g Wkv[e,256+g] * Wo[g,d] ),  e = blk-256, d = t
        int e = blk - 256;
        float acc = 0.f;
        #pragma unroll 8
        for (int g = 0; g < 256; ++g)
            acc = fmaf(Wkv[(long)e * 512 + 256 + g], Wo[g * 256 + t], acc);
        ((unsigned short*)(ws + WS_WVOBF))[t * 256 + e] = f2bf(acc);
    } else if (blk == 512) {
        float acc = 0.f;
        #pragma unroll 8
        for (int d = 0; d < 256; ++d)
            acc = fmaf(bq[d], Wkv[(long)t * 512 + d], acc);
        ws[WS_PB + t] = acc * 0.0625f;   // fold 1/sqrt(D) into p
    } else {
        float acc = 0.f;
        #pragma unroll 8
        for (int g = 0; g < 256; ++g)
            acc = fmaf(bkv[256 + g], Wo[g * 256 + t], acc);
        ws[WS_BVO + t] = acc;
    }
}

// ======================================================================================
// Fused row pipeline: LN -> p-GEMM -> sample/softmax -> out-GEMM -> store
// 32 rows per block, 8 waves (512 threads).
// GEMM phases: wave owns output cols [wave*32, wave*32+32), rows via mt in {0,1}.
// Phase 3: one row per 32-lane HALF-WAVE (lane covers 8 dims, uint4 gathers,
//          5-step butterfly, predicated online softmax).
//   REGISTER DISCIPLINE (round-4 spill post-mortem): row loop unroll 1 (one row's
//   state live), context loop unroll 2 (<=2 contexts of loads in flight),
//   launch_bounds(512,6) -> ~80 VGPR cap. LDS caps blocks at 4/CU anyway;
//   VGPR at 80 gives 3 blocks/CU = 24 waves/CU, no spill.
// One LDS slab reused across phases:
//   phase1: qs bf16   (row r at buf + r*SLOT, first 512 B of slot); residual in regs
//   phase2: p/16 fp32 (row r at buf + r*SLOT, 1024 B)   [sync before overwrite]
//   phase3: sbar bf16 (overlays p row r — safe: sbar data-depends on p reads, same half)
//   phase4: out fp32  tile (after sync)
// ======================================================================================
#define RPB  32
#define SLOT 260   // floats per row slot (1040 B)

__global__ __launch_bounds__(512, 6)
void fused_rowpipe(const float* __restrict__ queries, const float* __restrict__ gamma,
                   const float* __restrict__ beta, const float* __restrict__ coords,
                   const int* __restrict__ vmask, const float* __restrict__ bo,
                   const float* __restrict__ ws, float* __restrict__ out) {
    __shared__ float buf[RPB * SLOT + RPB];
    float* ssu = buf + RPB * SLOT;

    const unsigned short* Abf    = (const unsigned short*)(ws + WS_ABF);
    const unsigned short* Wvobf  = (const unsigned short*)(ws + WS_WVOBF);
    const float*          pb     = ws + WS_PB;
    const float*          bvo    = ws + WS_BVO;
    const unsigned short* featbf = (const unsigned short*)(ws + WS_FEATBF);

    int tid = threadIdx.x, wave = tid >> 6, lane = tid & 63;
    long row0 = (long)blockIdx.x * RPB;

    float4 qstash[4];   // residual rows for phase 5 (same addresses as phase 1 loads)

    // ---------------- phase 1: layernorm -> qs bf16 ----------------
    {
        float4 g4 = *(const float4*)(gamma + 4 * lane);
        float4 b4 = *(const float4*)(beta + 4 * lane);
        #pragma unroll
        for (int rr = 0; rr < 4; ++rr) {
            int r = wave * 4 + rr;
            float4 v = *(const float4*)(queries + (row0 + r) * 256 + 4 * lane);
            qstash[rr] = v;
            float s = v.x + v.y + v.z + v.w;
            s += __shfl_xor(s, 32); s += __shfl_xor(s, 16); s += __shfl_xor(s, 8);
            s += __shfl_xor(s, 4);  s += __shfl_xor(s, 2);  s += __shfl_xor(s, 1);
            float mu = s * 0.00390625f;
            float dx = v.x - mu, dy = v.y - mu, dz = v.z - mu, dw = v.w - mu;
            float vv = dx * dx + dy * dy + dz * dz + dw * dw;
            vv += __shfl_xor(vv, 32); vv += __shfl_xor(vv, 16); vv += __shfl_xor(vv, 8);
            vv += __shfl_xor(vv, 4);  vv += __shfl_xor(vv, 2);  vv += __shfl_xor(vv, 1);
            float rstd = rsqrtf(vv * 0.00390625f + 1e-5f);
            float qx = dx * rstd * g4.x + b4.x;
            float qy = dy * rstd * g4.y + b4.y;
            float qz = dz * rstd * g4.z + b4.z;
            float qw = dw * rstd * g4.w + b4.w;
            unsigned lo = (unsigned)f2bf(qx) | ((unsigned)f2bf(qy) << 16);
            unsigned hi = (unsigned)f2bf(qz) | ((unsigned)f2bf(qw) << 16);
            *(uint2*)((unsigned short*)&buf[r * SLOT] + 4 * lane) = make_uint2(lo, hi);
        }
    }
    __syncthreads();

    int r16 = lane & 15, g = lane >> 4;
    f32x4 zero = {0.f, 0.f, 0.f, 0.f};

    // ---------------- phase 2: p = (LN(q) @ A^T + pb)/16  (MFMA) ----------------
    {
        f32x4 acc[2][2];
        #pragma unroll
        for (int mt = 0; mt < 2; ++mt)
            #pragma unroll
            for (int nt = 0; nt < 2; ++nt) acc[mt][nt] = zero;

        #pragma unroll
        for (int ks = 0; ks < 8; ++ks) {
            short8 bfr[2], afr[2];
            #pragma unroll
            for (int nt = 0; nt < 2; ++nt)
                bfr[nt] = *(const short8*)(Abf + ((wave * 32 + nt * 16 + r16) << 8) + ks * 32 + g * 8);
            #pragma unroll
            for (int mt = 0; mt < 2; ++mt)
                afr[mt] = *(const short8*)((const unsigned short*)buf + (mt * 16 + r16) * (SLOT * 2) + ks * 32 + g * 8);
            #pragma unroll
            for (int mt = 0; mt < 2; ++mt)
                #pragma unroll
                for (int nt = 0; nt < 2; ++nt)
                    acc[mt][nt] = __builtin_amdgcn_mfma_f32_16x16x32_bf16(afr[mt], bfr[nt], acc[mt][nt], 0, 0, 0);
        }
        __syncthreads();   // all qs reads complete before overwriting slab with p

        float pbv[2];
        #pragma unroll
        for (int nt = 0; nt < 2; ++nt) pbv[nt] = pb[wave * 32 + nt * 16 + r16];
        #pragma unroll
        for (int mt = 0; mt < 2; ++mt)
            #pragma unroll
            for (int nt = 0; nt < 2; ++nt)
                #pragma unroll
                for (int rg = 0; rg < 4; ++rg)
                    buf[(mt * 16 + g * 4 + rg) * SLOT + wave * 32 + nt * 16 + r16] =
                        acc[mt][nt][rg] * 0.0625f + pbv[nt];
    }
    __syncthreads();

    // ---------------- phase 3: sample + score + online softmax (half-wave/row) --------
    {
        int half = lane >> 5, l5 = lane & 31;
        #pragma unroll 1
        for (int it = 0; it < 2; ++it) {
            int r = wave * 4 + it * 2 + half;
            long rowl = row0 + r;
            int b = (int)(rowl >> 14);
            int n = (int)(rowl & 16383);

            float4 pA = *(const float4*)(&buf[r * SLOT + 8 * l5]);
            float4 pB = *(const float4*)(&buf[r * SLOT + 8 * l5 + 4]);

            float m = -INFINITY, ssum = 0.f;
            float4 sA = {0.f, 0.f, 0.f, 0.f}, sB = {0.f, 0.f, 0.f, 0.f};

            #pragma unroll 2
            for (int c = 0; c < 8; ++c) {
                long cb = (long)(b * 8 + c) * 16384 + n;
                float cx = coords[2 * cb];
                float cy = coords[2 * cb + 1];
                bool vld = (vmask[cb] != 0);
                float x = (cx + 1.f) * 31.5f;
                float y = (cy + 1.f) * 31.5f;
                float x0f = floorf(x), y0f = floorf(y);
                float wx = x - x0f, wy = y - y0f;
                int ix0 = (int)x0f, iy0 = (int)y0f;
                int ix1 = ix0 + 1, iy1 = iy0 + 1;
                float bx0 = (ix0 >= 0 && ix0 < 64) ? 1.f : 0.f;
                float bx1 = (ix1 >= 0 && ix1 < 64) ? 1.f : 0.f;
                float by0 = (iy0 >= 0 && iy0 < 64) ? 1.f : 0.f;
                float by1 = (iy1 >= 0 && iy1 < 64) ? 1.f : 0.f;
                int cx0 = min(max(ix0, 0), 63), cx1 = min(max(ix1, 0), 63);
                int cy0 = min(max(iy0, 0), 63), cy1 = min(max(iy1, 0), 63);
                const unsigned short* fb = featbf + ((long)(b * 8 + c) << 20);
                uint4 v00 = *((const uint4*)(fb + ((cy0 * 64 + cx0) << 8)) + l5);
                uint4 v01 = *((const uint4*)(fb + ((cy0 * 64 + cx1) << 8)) + l5);
                uint4 v10 = *((const uint4*)(fb + ((cy1 * 64 + cx0) << 8)) + l5);
                uint4 v11 = *((const uint4*)(fb + ((cy1 * 64 + cx1) << 8)) + l5);
                float w00 = (1.f - wy) * (1.f - wx) * by0 * bx0;
                float w01 = (1.f - wy) * wx * by0 * bx1;
                float w10 = wy * (1.f - wx) * by1 * bx0;
                float w11 = wy * wx * by1 * bx1;
                float s0 = w00*bf_lo(v00.x) + w01*bf_lo(v01.x) + w10*bf_lo(v10.x) + w11*bf_lo(v11.x);
                float s1 = w00*bf_hi(v00.x) + w01*bf_hi(v01.x) + w10*bf_hi(v10.x) + w11*bf_hi(v11.x);
                float s2 = w00*bf_lo(v00.y) + w01*bf_lo(v01.y) + w10*bf_lo(v10.y) + w11*bf_lo(v11.y);
                float s3 = w00*bf_hi(v00.y) + w01*bf_hi(v01.y) + w10*bf_hi(v10.y) + w11*bf_hi(v11.y);
                float s4 = w00*bf_lo(v00.z) + w01*bf_lo(v01.z) + w10*bf_lo(v10.z) + w11*bf_lo(v11.z);
                float s5 = w00*bf_hi(v00.z) + w01*bf_hi(v01.z) + w10*bf_hi(v10.z) + w11*bf_hi(v11.z);
                float s6 = w00*bf_lo(v00.w) + w01*bf_lo(v01.w) + w10*bf_lo(v10.w) + w11*bf_lo(v11.w);
                float s7 = w00*bf_hi(v00.w) + w01*bf_hi(v01.w) + w10*bf_hi(v10.w) + w11*bf_hi(v11.w);
                float t = s0 * pA.x + s1 * pA.y + s2 * pA.z + s3 * pA.w
                        + s4 * pB.x + s5 * pB.y + s6 * pB.z + s7 * pB.w;
                t += __shfl_xor(t, 16); t += __shfl_xor(t, 8); t += __shfl_xor(t, 4);
                t += __shfl_xor(t, 2);  t += __shfl_xor(t, 1);
                // predicated online softmax (NaN-guarded; 1/16 folded into p)
                float nm = vld ? fmaxf(m, t) : m;
                float d  = (m > -INFINITY) ? (m - nm) : 0.f;
                float scale = __expf(d);
                float w = vld ? __expf(t - nm) : 0.f;
                ssum = ssum * scale + w;
                sA.x = fmaf(w, s0, sA.x * scale);
                sA.y = fmaf(w, s1, sA.y * scale);
                sA.z = fmaf(w, s2, sA.z * scale);
                sA.w = fmaf(w, s3, sA.w * scale);
                sB.x = fmaf(w, s4, sB.x * scale);
                sB.y = fmaf(w, s5, sB.y * scale);
                sB.z = fmaf(w, s6, sB.z * scale);
                sB.w = fmaf(w, s7, sB.w * scale);
                m = nm;
            }

            float inv = (m > -INFINITY) ? (1.f / ssum) : 0.f;
            float sa  = (m > -INFINITY) ? 1.f : 0.f;
            // sbar bf16 overlays this row's p storage (data-depends on p reads, same half)
            uint4 o;
            o.x = (unsigned)f2bf(sA.x * inv) | ((unsigned)f2bf(sA.y * inv) << 16);
            o.y = (unsigned)f2bf(sA.z * inv) | ((unsigned)f2bf(sA.w * inv) << 16);
            o.z = (unsigned)f2bf(sB.x * inv) | ((unsigned)f2bf(sB.y * inv) << 16);
            o.w = (unsigned)f2bf(sB.z * inv) | ((unsigned)f2bf(sB.w * inv) << 16);
            *(uint4*)((unsigned short*)&buf[r * SLOT] + 8 * l5) = o;
            if (l5 == 0) ssu[r] = sa;
        }
    }
    __syncthreads();

    // ---------------- phase 4: out-GEMM: sbar @ Wvo^T  (MFMA) ----------------
    {
        f32x4 acc2[2][2];
        #pragma unroll
        for (int mt = 0; mt < 2; ++mt)
            #pragma unroll
            for (int nt = 0; nt < 2; ++nt) acc2[mt][nt] = zero;

        #pragma unroll
        for (int ks = 0; ks < 8; ++ks) {
            short8 bfr[2], afr[2];
            #pragma unroll
            for (int nt = 0; nt < 2; ++nt)
                bfr[nt] = *(const short8*)(Wvobf + ((wave * 32 + nt * 16 + r16) << 8) + ks * 32 + g * 8);
            #pragma unroll
            for (int mt = 0; mt < 2; ++mt)
                afr[mt] = *(const short8*)((const unsigned short*)buf + (mt * 16 + r16) * (SLOT * 2) + ks * 32 + g * 8);
            #pragma unroll
            for (int mt = 0; mt < 2; ++mt)
                #pragma unroll
                for (int nt = 0; nt < 2; ++nt)
                    acc2[mt][nt] = __builtin_amdgcn_mfma_f32_16x16x32_bf16(afr[mt], bfr[nt], acc2[mt][nt], 0, 0, 0);
        }
        __syncthreads();   // all sbar reads complete before overwriting slab with out tile

        #pragma unroll
        for (int mt = 0; mt < 2; ++mt)
            #pragma unroll
            for (int nt = 0; nt < 2; ++nt)
                #pragma unroll
                for (int rg = 0; rg < 4; ++rg)
                    buf[(mt * 16 + g * 4 + rg) * SLOT + wave * 32 + nt * 16 + r16] = acc2[mt][nt][rg];
    }
    __syncthreads();

    // ---------------- phase 5: out = residual + tile + suma*bvo + bo  (float4 stores) --
    {
        float4 bvo4 = *(const float4*)(bvo + 4 * lane);
        float4 bo4  = *(const float4*)(bo + 4 * lane);
        #pragma unroll
        for (int rr = 0; rr < 4; ++rr) {
            int r = wave * 4 + rr;
            float4 q4 = qstash[rr];
            float4 a4 = *(const float4*)(&buf[r * SLOT + 4 * lane]);
            float su = ssu[r];
            float4 o;
            o.x = q4.x + a4.x + su * bvo4.x + bo4.x;
            o.y = q4.y + a4.y + su * bvo4.y + bo4.y;
            o.z = q4.z + a4.z + su * bvo4.z + bo4.z;
            o.w = q4.w + a4.w + su * bvo4.w + bo4.w;
            *(float4*)(out + (row0 + r) * 256 + 4 * lane) = o;
        }
    }
}

extern "C" void kernel_launch(void* const* d_in, const int* in_sizes, int n_in,
                              void* d_out, int out_size, void* d_ws, size_t ws_size,
                              hipStream_t stream) {
    const float* queries = (const float*)d_in[0];
    const float* feat    = (const float*)d_in[1];
    const float* coords  = (const float*)d_in[2];
    const int*   vmask   = (const int*)  d_in[3];
    const float* Wq      = (const float*)d_in[4];
    const float* bq      = (const float*)d_in[5];
    const float* Wkv     = (const float*)d_in[6];
    const float* bkv     = (const float*)d_in[7];
    const float* Wo      = (const float*)d_in[8];
    const float* bo      = (const float*)d_in[9];
    const float* gamma   = (const float*)d_in[10];
    const float* beta    = (const float*)d_in[11];
    float* out = (float*)d_out;
    float* ws  = (float*)d_ws;

    precompute_kernel<<<514 + 4096, 256, 0, stream>>>(Wq, bq, Wkv, bkv, Wo, feat, ws);
    fused_rowpipe<<<NROWS / RPB, 512, 0, stream>>>(queries, gamma, beta, coords, vmask, bo, ws, out);
}

// Round 7
// 267.603 us; speedup vs baseline: 2.5178x; 1.0406x over previous
//
#include <hip/hip_runtime.h>
#include <math.h>

// Shape: B=2 C=8 N=16384 D=256 H=W=64 ; rows = B*N = 32768
#define NROWS 32768

typedef __attribute__((ext_vector_type(8))) short short8;
typedef __attribute__((ext_vector_type(4))) float f32x4;

// Workspace layout (units of float):
//  ABF    ushort[256*256]  A^T in bf16:   Abf[e*256+f] = bf16(sum_d Wq[f,d]*Wk[e,d])
//  WVOBF  ushort[256*256]  Wvo^T in bf16: Wvobf[d*256+e] = bf16(sum_g Wv[e,g]*Wo[g,d])
//  PB     float[256]       bq @ Wk^T
//  BVO    float[256]       bv @ Wo
//  FEATBF ushort[2*8*64*64*256]  bf16 copy of image_features
#define WS_ABF    0
#define WS_WVOBF  32768
#define WS_PB     65536
#define WS_BVO    65792
#define WS_FEATBF 8487424

__device__ __forceinline__ unsigned short f2bf(float f) {
    unsigned u = __builtin_bit_cast(unsigned, f);
    u += 0x7FFFu + ((u >> 16) & 1u);          // RNE
    return (unsigned short)(u >> 16);
}
__device__ __forceinline__ float bf_lo(unsigned u) {
    return __builtin_bit_cast(float, u << 16);
}
__device__ __forceinline__ float bf_hi(unsigned u) {
    return __builtin_bit_cast(float, u & 0xFFFF0000u);
}

// ---------------- precompute: A^T(bf16), Wvo^T(bf16), pb, bvo, feat->bf16 -------------
// feat conversion: 4096 blocks, 16 floats (64 B) per thread -> streaming-efficient.
__global__ __launch_bounds__(256)
void precompute_kernel(const float* __restrict__ Wq, const float* __restrict__ bq,
                       const float* __restrict__ Wkv, const float* __restrict__ bkv,
                       const float* __restrict__ Wo, const float* __restrict__ feat,
                       float* __restrict__ ws) {
    int t = threadIdx.x;
    int blk = blockIdx.x;
    if (blk >= 514) {
        // feature map fp32 -> bf16, 4096 floats per block, 16 per thread
        long i = (long)(blk - 514) * 4096 + t * 16;
        const float4* src = (const float4*)(feat + i);
        unsigned short* dst = (unsigned short*)(ws + WS_FEATBF) + i;
        #pragma unroll
        for (int h = 0; h < 2; ++h) {
            float4 a = src[2 * h], b = src[2 * h + 1];
            uint4 o;
            o.x = (unsigned)f2bf(a.x) | ((unsigned)f2bf(a.y) << 16);
            o.y = (unsigned)f2bf(a.z) | ((unsigned)f2bf(a.w) << 16);
            o.z = (unsigned)f2bf(b.x) | ((unsigned)f2bf(b.y) << 16);
            o.w = (unsigned)f2bf(b.z) | ((unsigned)f2bf(b.w) << 16);
            *(uint4*)(dst + 8 * h) = o;
        }
        return;
    }
    if (blk < 256) {
        // Abf[e][f] = bf16( Wq[f,:] . Wk[e,:] ),  f = blk, e = t
        int f = blk;
        const float4* wq4 = (const float4*)(Wq + f * 256);
        const float4* wk4 = (const float4*)(Wkv + (long)t * 512);
        float acc = 0.f;
        #pragma unroll 8
        for (int d4 = 0; d4 < 64; ++d4) {
            float4 a = wq4[d4], b = wk4[d4];
            acc += a.x * b.x + a.y * b.y + a.z * b.z + a.w * b.w;
        }
        ((unsigned short*)(ws + WS_ABF))[t * 256 + f] = f2bf(acc);
    } else if (blk < 512) {
        // Wvobf[d][e] = bf16( sum_g Wkv[e,256+g] * Wo[g,d] ),  e = blk-256, d = t
        int e = blk - 256;
        float acc = 0.f;
        #pragma unroll 8
        for (int g = 0; g < 256; ++g)
            acc = fmaf(Wkv[(long)e * 512 + 256 + g], Wo[g * 256 + t], acc);
        ((unsigned short*)(ws + WS_WVOBF))[t * 256 + e] = f2bf(acc);
    } else if (blk == 512) {
        float acc = 0.f;
        #pragma unroll 8
        for (int d = 0; d < 256; ++d)
            acc = fmaf(bq[d], Wkv[(long)t * 512 + d], acc);
        ws[WS_PB + t] = acc;
    } else {
        float acc = 0.f;
        #pragma unroll 8
        for (int g = 0; g < 256; ++g)
            acc = fmaf(bkv[256 + g], Wo[g * 256 + t], acc);
        ws[WS_BVO + t] = acc;
    }
}

// ======================================================================================
// Fused row pipeline: LN -> p-GEMM -> sample/softmax -> out-GEMM -> store
// 32 rows per block, 8 waves (512 threads). Row-phases: 4 rows/wave.
// GEMM phases: wave owns output cols [wave*32, wave*32+32), rows via mt in {0,1}.
// LDS 33.4 KB -> 4 blocks/CU x 8 waves = 32 waves/CU (100% occupancy cap).
// One LDS slab reused across phases:
//   phase1: qs bf16   (row r at buf + r*SLOT, first 512 B of slot); residual in regs
//   phase2: p   fp32  (row r at buf + r*SLOT, 1024 B)   [sync before overwrite]
//   phase3: sbar bf16 (overlays p row r — safe: sbar data-depends on p reads, same wave)
//   phase4: out fp32  tile (after sync)
// ======================================================================================
#define RPB  32
#define SLOT 260   // floats per row slot (1040 B)

__global__ __launch_bounds__(512, 8)
void fused_rowpipe(const float* __restrict__ queries, const float* __restrict__ gamma,
                   const float* __restrict__ beta, const float* __restrict__ coords,
                   const int* __restrict__ vmask, const float* __restrict__ bo,
                   const float* __restrict__ ws, float* __restrict__ out) {
    __shared__ float buf[RPB * SLOT + RPB];
    float* ssu = buf + RPB * SLOT;

    const unsigned short* Abf    = (const unsigned short*)(ws + WS_ABF);
    const unsigned short* Wvobf  = (const unsigned short*)(ws + WS_WVOBF);
    const float*          pb     = ws + WS_PB;
    const float*          bvo    = ws + WS_BVO;
    const unsigned short* featbf = (const unsigned short*)(ws + WS_FEATBF);

    int tid = threadIdx.x, wave = tid >> 6, lane = tid & 63;
    long row0 = (long)blockIdx.x * RPB;

    float4 qstash[4];   // residual rows for phase 5 (same addresses as phase 1 loads)

    // ---------------- phase 1: layernorm -> qs bf16 ----------------
    {
        float4 g4 = *(const float4*)(gamma + 4 * lane);
        float4 b4 = *(const float4*)(beta + 4 * lane);
        #pragma unroll
        for (int rr = 0; rr < 4; ++rr) {
            int r = wave * 4 + rr;
            float4 v = *(const float4*)(queries + (row0 + r) * 256 + 4 * lane);
            qstash[rr] = v;
            float s = v.x + v.y + v.z + v.w;
            s += __shfl_xor(s, 32); s += __shfl_xor(s, 16); s += __shfl_xor(s, 8);
            s += __shfl_xor(s, 4);  s += __shfl_xor(s, 2);  s += __shfl_xor(s, 1);
            float mu = s * 0.00390625f;
            float dx = v.x - mu, dy = v.y - mu, dz = v.z - mu, dw = v.w - mu;
            float vv = dx * dx + dy * dy + dz * dz + dw * dw;
            vv += __shfl_xor(vv, 32); vv += __shfl_xor(vv, 16); vv += __shfl_xor(vv, 8);
            vv += __shfl_xor(vv, 4);  vv += __shfl_xor(vv, 2);  vv += __shfl_xor(vv, 1);
            float rstd = rsqrtf(vv * 0.00390625f + 1e-5f);
            float qx = dx * rstd * g4.x + b4.x;
            float qy = dy * rstd * g4.y + b4.y;
            float qz = dz * rstd * g4.z + b4.z;
            float qw = dw * rstd * g4.w + b4.w;
            unsigned lo = (unsigned)f2bf(qx) | ((unsigned)f2bf(qy) << 16);
            unsigned hi = (unsigned)f2bf(qz) | ((unsigned)f2bf(qw) << 16);
            *(uint2*)((unsigned short*)&buf[r * SLOT] + 4 * lane) = make_uint2(lo, hi);
        }
    }
    __syncthreads();

    int r16 = lane & 15, g = lane >> 4;
    f32x4 zero = {0.f, 0.f, 0.f, 0.f};

    // ---------------- phase 2: p = LN(q) @ A^T + pb  (MFMA) ----------------
    {
        f32x4 acc[2][2];
        #pragma unroll
        for (int mt = 0; mt < 2; ++mt)
            #pragma unroll
            for (int nt = 0; nt < 2; ++nt) acc[mt][nt] = zero;

        #pragma unroll
        for (int ks = 0; ks < 8; ++ks) {
            short8 bfr[2], afr[2];
            #pragma unroll
            for (int nt = 0; nt < 2; ++nt)
                bfr[nt] = *(const short8*)(Abf + ((wave * 32 + nt * 16 + r16) << 8) + ks * 32 + g * 8);
            #pragma unroll
            for (int mt = 0; mt < 2; ++mt)
                afr[mt] = *(const short8*)((const unsigned short*)buf + (mt * 16 + r16) * (SLOT * 2) + ks * 32 + g * 8);
            #pragma unroll
            for (int mt = 0; mt < 2; ++mt)
                #pragma unroll
                for (int nt = 0; nt < 2; ++nt)
                    acc[mt][nt] = __builtin_amdgcn_mfma_f32_16x16x32_bf16(afr[mt], bfr[nt], acc[mt][nt], 0, 0, 0);
        }
        __syncthreads();   // all qs reads complete before overwriting slab with p

        float pbv[2];
        #pragma unroll
        for (int nt = 0; nt < 2; ++nt) pbv[nt] = pb[wave * 32 + nt * 16 + r16];
        #pragma unroll
        for (int mt = 0; mt < 2; ++mt)
            #pragma unroll
            for (int nt = 0; nt < 2; ++nt)
                #pragma unroll
                for (int rg = 0; rg < 4; ++rg)
                    buf[(mt * 16 + g * 4 + rg) * SLOT + wave * 32 + nt * 16 + r16] =
                        acc[mt][nt][rg] + pbv[nt];
    }
    __syncthreads();

    // ---------------- phase 3: sample + score + online softmax ----------------
    for (int rr = 0; rr < 4; ++rr) {
        int r = wave * 4 + rr;
        int rowu = __builtin_amdgcn_readfirstlane((int)(row0 + r));
        int b = rowu >> 14;
        int n = rowu & 16383;

        float4 p4 = *(const float4*)(&buf[r * SLOT + 4 * lane]);

        // online softmax state (all wave-uniform branches: vld/score uniform per wave)
        float m = -INFINITY, ssum = 0.f;
        float4 sbacc = {0.f, 0.f, 0.f, 0.f};

        #pragma unroll
        for (int c = 0; c < 8; ++c) {
            long cb = (long)(b * 8 + c) * 16384 + n;
            float cx = coords[2 * cb];
            float cy = coords[2 * cb + 1];
            bool vld = (vmask[cb] != 0);
            float x = (cx + 1.f) * 31.5f;
            float y = (cy + 1.f) * 31.5f;
            float x0f = floorf(x), y0f = floorf(y);
            float wx = x - x0f, wy = y - y0f;
            int ix0 = (int)x0f, iy0 = (int)y0f;
            int ix1 = ix0 + 1, iy1 = iy0 + 1;
            float bx0 = (ix0 >= 0 && ix0 < 64) ? 1.f : 0.f;
            float bx1 = (ix1 >= 0 && ix1 < 64) ? 1.f : 0.f;
            float by0 = (iy0 >= 0 && iy0 < 64) ? 1.f : 0.f;
            float by1 = (iy1 >= 0 && iy1 < 64) ? 1.f : 0.f;
            int cx0 = min(max(ix0, 0), 63), cx1 = min(max(ix1, 0), 63);
            int cy0 = min(max(iy0, 0), 63), cy1 = min(max(iy1, 0), 63);
            const unsigned short* fb = featbf + ((long)(b * 8 + c) << 20);
            const uint2* r00 = (const uint2*)(fb + ((cy0 * 64 + cx0) << 8)) + lane;
            const uint2* r01 = (const uint2*)(fb + ((cy0 * 64 + cx1) << 8)) + lane;
            const uint2* r10 = (const uint2*)(fb + ((cy1 * 64 + cx0) << 8)) + lane;
            const uint2* r11 = (const uint2*)(fb + ((cy1 * 64 + cx1) << 8)) + lane;
            float w00 = (1.f - wy) * (1.f - wx) * by0 * bx0;
            float w01 = (1.f - wy) * wx * by0 * bx1;
            float w10 = wy * (1.f - wx) * by1 * bx0;
            float w11 = wy * wx * by1 * bx1;
            uint2 v00 = *r00, v01 = *r01, v10 = *r10, v11 = *r11;
            float4 s;
            s.x = w00 * bf_lo(v00.x) + w01 * bf_lo(v01.x) + w10 * bf_lo(v10.x) + w11 * bf_lo(v11.x);
            s.y = w00 * bf_hi(v00.x) + w01 * bf_hi(v01.x) + w10 * bf_hi(v10.x) + w11 * bf_hi(v11.x);
            s.z = w00 * bf_lo(v00.y) + w01 * bf_lo(v01.y) + w10 * bf_lo(v10.y) + w11 * bf_lo(v11.y);
            s.w = w00 * bf_hi(v00.y) + w01 * bf_hi(v01.y) + w10 * bf_hi(v10.y) + w11 * bf_hi(v11.y);
            float t = s.x * p4.x + s.y * p4.y + s.z * p4.z + s.w * p4.w;
            t += __shfl_xor(t, 32); t += __shfl_xor(t, 16); t += __shfl_xor(t, 8);
            t += __shfl_xor(t, 4);  t += __shfl_xor(t, 2);  t += __shfl_xor(t, 1);
            t *= 0.0625f;
            if (vld) {               // wave-uniform
                float nm = fmaxf(m, t);
                float scale = __expf(m - nm);     // m=-inf -> 0 on first valid ctx
                float w = __expf(t - nm);
                ssum = ssum * scale + w;
                sbacc.x = fmaf(w, s.x, sbacc.x * scale);
                sbacc.y = fmaf(w, s.y, sbacc.y * scale);
                sbacc.z = fmaf(w, s.z, sbacc.z * scale);
                sbacc.w = fmaf(w, s.w, sbacc.w * scale);
                m = nm;
            }
        }

        float4 sb = {0.f, 0.f, 0.f, 0.f};
        float sa = 0.f;
        if (m > -INFINITY) {        // wave-uniform
            float inv = 1.f / ssum;
            sb.x = sbacc.x * inv;
            sb.y = sbacc.y * inv;
            sb.z = sbacc.z * inv;
            sb.w = sbacc.w * inv;
            sa = 1.f;
        }
        // sbar bf16 overlays this row's p storage (safe: values data-depend on p4 reads)
        unsigned lo = (unsigned)f2bf(sb.x) | ((unsigned)f2bf(sb.y) << 16);
        unsigned hi = (unsigned)f2bf(sb.z) | ((unsigned)f2bf(sb.w) << 16);
        *(uint2*)((unsigned short*)&buf[r * SLOT] + 4 * lane) = make_uint2(lo, hi);
        if (lane == 0) ssu[r] = sa;
    }
    __syncthreads();

    // ---------------- phase 4: out-GEMM: sbar @ Wvo^T  (MFMA) ----------------
    {
        f32x4 acc2[2][2];
        #pragma unroll
        for (int mt = 0; mt < 2; ++mt)
            #pragma unroll
            for (int nt = 0; nt < 2; ++nt) acc2[mt][nt] = zero;

        #pragma unroll
        for (int ks = 0; ks < 8; ++ks) {
            short8 bfr[2], afr[2];
            #pragma unroll
            for (int nt = 0; nt < 2; ++nt)
                bfr[nt] = *(const short8*)(Wvobf + ((wave * 32 + nt * 16 + r16) << 8) + ks * 32 + g * 8);
            #pragma unroll
            for (int mt = 0; mt < 2; ++mt)
                afr[mt] = *(const short8*)((const unsigned short*)buf + (mt * 16 + r16) * (SLOT * 2) + ks * 32 + g * 8);
            #pragma unroll
            for (int mt = 0; mt < 2; ++mt)
                #pragma unroll
                for (int nt = 0; nt < 2; ++nt)
                    acc2[mt][nt] = __builtin_amdgcn_mfma_f32_16x16x32_bf16(afr[mt], bfr[nt], acc2[mt][nt], 0, 0, 0);
        }
        __syncthreads();   // all sbar reads complete before overwriting slab with out tile

        #pragma unroll
        for (int mt = 0; mt < 2; ++mt)
            #pragma unroll
            for (int nt = 0; nt < 2; ++nt)
                #pragma unroll
                for (int rg = 0; rg < 4; ++rg)
                    buf[(mt * 16 + g * 4 + rg) * SLOT + wave * 32 + nt * 16 + r16] = acc2[mt][nt][rg];
    }
    __syncthreads();

    // ---------------- phase 5: out = residual + tile + suma*bvo + bo  (float4 stores) --
    {
        float4 bvo4 = *(const float4*)(bvo + 4 * lane);
        float4 bo4  = *(const float4*)(bo + 4 * lane);
        #pragma unroll
        for (int rr = 0; rr < 4; ++rr) {
            int r = wave * 4 + rr;
            float4 q4 = qstash[rr];
            float4 a4 = *(const float4*)(&buf[r * SLOT + 4 * lane]);
            float su = ssu[r];
            float4 o;
            o.x = q4.x + a4.x + su * bvo4.x + bo4.x;
            o.y = q4.y + a4.y + su * bvo4.y + bo4.y;
            o.z = q4.z + a4.z + su * bvo4.z + bo4.z;
            o.w = q4.w + a4.w + su * bvo4.w + bo4.w;
            *(float4*)(out + (row0 + r) * 256 + 4 * lane) = o;
        }
    }
}

extern "C" void kernel_launch(void* const* d_in, const int* in_sizes, int n_in,
                              void* d_out, int out_size, void* d_ws, size_t ws_size,
                              hipStream_t stream) {
    const float* queries = (const float*)d_in[0];
    const float* feat    = (const float*)d_in[1];
    const float* coords  = (const float*)d_in[2];
    const int*   vmask   = (const int*)  d_in[3];
    const float* Wq      = (const float*)d_in[4];
    const float* bq      = (const float*)d_in[5];
    const float* Wkv     = (const float*)d_in[6];
    const float* bkv     = (const float*)d_in[7];
    const float* Wo      = (const float*)d_in[8];
    const float* bo      = (const float*)d_in[9];
    const float* gamma   = (const float*)d_in[10];
    const float* beta    = (const float*)d_in[11];
    float* out = (float*)d_out;
    float* ws  = (float*)d_ws;

    precompute_kernel<<<514 + 4096, 256, 0, stream>>>(Wq, bq, Wkv, bkv, Wo, feat, ws);
    fused_rowpipe<<<NROWS / RPB, 512, 0, stream>>>(queries, gamma, beta, coords, vmask, bo, ws, out);
}

// Round 8
// 253.040 us; speedup vs baseline: 2.6627x; 1.0576x over previous
//
#include <hip/hip_runtime.h>
#include <math.h>

// Shape: B=2 C=8 N=16384 D=256 H=W=64 ; rows = B*N = 32768
#define NROWS 32768

typedef __attribute__((ext_vector_type(8))) short short8;
typedef __attribute__((ext_vector_type(4))) float f32x4;

// Workspace layout (units of float):
//  ABF    ushort[256*256]  A^T in bf16:   Abf[e*256+f] = bf16(sum_d Wq[f,d]*Wk[e,d])
//  WVOBF  ushort[256*256]  Wvo^T in bf16: Wvobf[d*256+e] = bf16(sum_g Wv[e,g]*Wo[g,d])
//  PB     float[256]       bq @ Wk^T
//  BVO    float[256]       bv @ Wo
//  FEATBF ushort[2*8*64*64*256]  bf16 copy of image_features
#define WS_ABF    0
#define WS_WVOBF  32768
#define WS_PB     65536
#define WS_BVO    65792
#define WS_FEATBF 8487424

__device__ __forceinline__ unsigned short f2bf(float f) {
    unsigned u = __builtin_bit_cast(unsigned, f);
    u += 0x7FFFu + ((u >> 16) & 1u);          // RNE
    return (unsigned short)(u >> 16);
}
__device__ __forceinline__ float bf_lo(unsigned u) {
    return __builtin_bit_cast(float, u << 16);
}
__device__ __forceinline__ float bf_hi(unsigned u) {
    return __builtin_bit_cast(float, u & 0xFFFF0000u);
}

// ---------------- precompute: A^T(bf16), Wvo^T(bf16), pb, bvo, feat->bf16 -------------
// feat conversion: 4096 blocks, 16 floats (64 B) per thread -> streaming-efficient.
__global__ __launch_bounds__(256)
void precompute_kernel(const float* __restrict__ Wq, const float* __restrict__ bq,
                       const float* __restrict__ Wkv, const float* __restrict__ bkv,
                       const float* __restrict__ Wo, const float* __restrict__ feat,
                       float* __restrict__ ws) {
    int t = threadIdx.x;
    int blk = blockIdx.x;
    if (blk >= 514) {
        // feature map fp32 -> bf16, 4096 floats per block, 16 per thread
        long i = (long)(blk - 514) * 4096 + t * 16;
        const float4* src = (const float4*)(feat + i);
        unsigned short* dst = (unsigned short*)(ws + WS_FEATBF) + i;
        #pragma unroll
        for (int h = 0; h < 2; ++h) {
            float4 a = src[2 * h], b = src[2 * h + 1];
            uint4 o;
            o.x = (unsigned)f2bf(a.x) | ((unsigned)f2bf(a.y) << 16);
            o.y = (unsigned)f2bf(a.z) | ((unsigned)f2bf(a.w) << 16);
            o.z = (unsigned)f2bf(b.x) | ((unsigned)f2bf(b.y) << 16);
            o.w = (unsigned)f2bf(b.z) | ((unsigned)f2bf(b.w) << 16);
            *(uint4*)(dst + 8 * h) = o;
        }
        return;
    }
    if (blk < 256) {
        // Abf[e][f] = bf16( Wq[f,:] . Wk[e,:] ),  f = blk, e = t
        int f = blk;
        const float4* wq4 = (const float4*)(Wq + f * 256);
        const float4* wk4 = (const float4*)(Wkv + (long)t * 512);
        float acc = 0.f;
        #pragma unroll 8
        for (int d4 = 0; d4 < 64; ++d4) {
            float4 a = wq4[d4], b = wk4[d4];
            acc += a.x * b.x + a.y * b.y + a.z * b.z + a.w * b.w;
        }
        ((unsigned short*)(ws + WS_ABF))[t * 256 + f] = f2bf(acc);
    } else if (blk < 512) {
        // Wvobf[d][e] = bf16( sum_g Wkv[e,256+g] * Wo[g,d] ),  e = blk-256, d = t
        int e = blk - 256;
        float acc = 0.f;
        #pragma unroll 8
        for (int g = 0; g < 256; ++g)
            acc = fmaf(Wkv[(long)e * 512 + 256 + g], Wo[g * 256 + t], acc);
        ((unsigned short*)(ws + WS_WVOBF))[t * 256 + e] = f2bf(acc);
    } else if (blk == 512) {
        float acc = 0.f;
        #pragma unroll 8
        for (int d = 0; d < 256; ++d)
            acc = fmaf(bq[d], Wkv[(long)t * 512 + d], acc);
        ws[WS_PB + t] = acc;
    } else {
        float acc = 0.f;
        #pragma unroll 8
        for (int g = 0; g < 256; ++g)
            acc = fmaf(bkv[256 + g], Wo[g * 256 + t], acc);
        ws[WS_BVO + t] = acc;
    }
}

// ======================================================================================
// Fused row pipeline: LN -> p-GEMM -> sample/softmax -> out-GEMM -> store
// 32 rows per block, 8 waves (512 threads). Row-phases: 4 rows/wave.
// GEMM phases: wave owns output cols [wave*32, wave*32+32), rows via mt in {0,1}.
// LDS 33.4 KB -> 4 blocks/CU x 8 waves = 32 waves/CU (100% occupancy cap).
// Phase 3 NEW this round: whole gather+dot+reduce is inside a WAVE-UNIFORM
//   `if (vmask)` branch (cb provably uniform via readfirstlane'd row) —
//   ~50% of contexts are invalid and are now skipped entirely (scalar branch,
//   no divergence). Numerically identical: skipped ctx contributed w=0 exactly.
// One LDS slab reused across phases:
//   phase1: qs bf16   (row r at buf + r*SLOT, first 512 B of slot); residual in regs
//   phase2: p   fp32  (row r at buf + r*SLOT, 1024 B)   [sync before overwrite]
//   phase3: sbar bf16 (overlays p row r — safe: sbar data-depends on p reads, same wave)
//   phase4: out fp32  tile (after sync)
// ======================================================================================
#define RPB  32
#define SLOT 260   // floats per row slot (1040 B)

__global__ __launch_bounds__(512, 8)
void fused_rowpipe(const float* __restrict__ queries, const float* __restrict__ gamma,
                   const float* __restrict__ beta, const float* __restrict__ coords,
                   const int* __restrict__ vmask, const float* __restrict__ bo,
                   const float* __restrict__ ws, float* __restrict__ out) {
    __shared__ float buf[RPB * SLOT + RPB];
    float* ssu = buf + RPB * SLOT;

    const unsigned short* Abf    = (const unsigned short*)(ws + WS_ABF);
    const unsigned short* Wvobf  = (const unsigned short*)(ws + WS_WVOBF);
    const float*          pb     = ws + WS_PB;
    const float*          bvo    = ws + WS_BVO;
    const unsigned short* featbf = (const unsigned short*)(ws + WS_FEATBF);

    int tid = threadIdx.x, wave = tid >> 6, lane = tid & 63;
    long row0 = (long)blockIdx.x * RPB;

    float4 qstash[4];   // residual rows for phase 5 (same addresses as phase 1 loads)

    // ---------------- phase 1: layernorm -> qs bf16 ----------------
    {
        float4 g4 = *(const float4*)(gamma + 4 * lane);
        float4 b4 = *(const float4*)(beta + 4 * lane);
        #pragma unroll
        for (int rr = 0; rr < 4; ++rr) {
            int r = wave * 4 + rr;
            float4 v = *(const float4*)(queries + (row0 + r) * 256 + 4 * lane);
            qstash[rr] = v;
            float s = v.x + v.y + v.z + v.w;
            s += __shfl_xor(s, 32); s += __shfl_xor(s, 16); s += __shfl_xor(s, 8);
            s += __shfl_xor(s, 4);  s += __shfl_xor(s, 2);  s += __shfl_xor(s, 1);
            float mu = s * 0.00390625f;
            float dx = v.x - mu, dy = v.y - mu, dz = v.z - mu, dw = v.w - mu;
            float vv = dx * dx + dy * dy + dz * dz + dw * dw;
            vv += __shfl_xor(vv, 32); vv += __shfl_xor(vv, 16); vv += __shfl_xor(vv, 8);
            vv += __shfl_xor(vv, 4);  vv += __shfl_xor(vv, 2);  vv += __shfl_xor(vv, 1);
            float rstd = rsqrtf(vv * 0.00390625f + 1e-5f);
            float qx = dx * rstd * g4.x + b4.x;
            float qy = dy * rstd * g4.y + b4.y;
            float qz = dz * rstd * g4.z + b4.z;
            float qw = dw * rstd * g4.w + b4.w;
            unsigned lo = (unsigned)f2bf(qx) | ((unsigned)f2bf(qy) << 16);
            unsigned hi = (unsigned)f2bf(qz) | ((unsigned)f2bf(qw) << 16);
            *(uint2*)((unsigned short*)&buf[r * SLOT] + 4 * lane) = make_uint2(lo, hi);
        }
    }
    __syncthreads();

    int r16 = lane & 15, g = lane >> 4;
    f32x4 zero = {0.f, 0.f, 0.f, 0.f};

    // ---------------- phase 2: p = LN(q) @ A^T + pb  (MFMA) ----------------
    {
        f32x4 acc[2][2];
        #pragma unroll
        for (int mt = 0; mt < 2; ++mt)
            #pragma unroll
            for (int nt = 0; nt < 2; ++nt) acc[mt][nt] = zero;

        #pragma unroll
        for (int ks = 0; ks < 8; ++ks) {
            short8 bfr[2], afr[2];
            #pragma unroll
            for (int nt = 0; nt < 2; ++nt)
                bfr[nt] = *(const short8*)(Abf + ((wave * 32 + nt * 16 + r16) << 8) + ks * 32 + g * 8);
            #pragma unroll
            for (int mt = 0; mt < 2; ++mt)
                afr[mt] = *(const short8*)((const unsigned short*)buf + (mt * 16 + r16) * (SLOT * 2) + ks * 32 + g * 8);
            #pragma unroll
            for (int mt = 0; mt < 2; ++mt)
                #pragma unroll
                for (int nt = 0; nt < 2; ++nt)
                    acc[mt][nt] = __builtin_amdgcn_mfma_f32_16x16x32_bf16(afr[mt], bfr[nt], acc[mt][nt], 0, 0, 0);
        }
        __syncthreads();   // all qs reads complete before overwriting slab with p

        float pbv[2];
        #pragma unroll
        for (int nt = 0; nt < 2; ++nt) pbv[nt] = pb[wave * 32 + nt * 16 + r16];
        #pragma unroll
        for (int mt = 0; mt < 2; ++mt)
            #pragma unroll
            for (int nt = 0; nt < 2; ++nt)
                #pragma unroll
                for (int rg = 0; rg < 4; ++rg)
                    buf[(mt * 16 + g * 4 + rg) * SLOT + wave * 32 + nt * 16 + r16] =
                        acc[mt][nt][rg] + pbv[nt];
    }
    __syncthreads();

    // ---------------- phase 3: sample + score + online softmax ----------------
    for (int rr = 0; rr < 4; ++rr) {
        int r = wave * 4 + rr;
        int rowu = __builtin_amdgcn_readfirstlane((int)(row0 + r));
        int b = rowu >> 14;
        int n = rowu & 16383;

        float4 p4 = *(const float4*)(&buf[r * SLOT + 4 * lane]);

        // online softmax state (all branches wave-uniform: cb/vld uniform per wave)
        float m = -INFINITY, ssum = 0.f;
        float4 sbacc = {0.f, 0.f, 0.f, 0.f};

        #pragma unroll
        for (int c = 0; c < 8; ++c) {
            int cb = ((b * 8 + c) << 14) | n;      // wave-uniform
            if (vmask[cb] != 0) {                   // wave-uniform branch: skip ~50% ctx
                float cx = coords[2 * (long)cb];
                float cy = coords[2 * (long)cb + 1];
                float x = (cx + 1.f) * 31.5f;
                float y = (cy + 1.f) * 31.5f;
                float x0f = floorf(x), y0f = floorf(y);
                float wx = x - x0f, wy = y - y0f;
                int ix0 = (int)x0f, iy0 = (int)y0f;
                int ix1 = ix0 + 1, iy1 = iy0 + 1;
                float bx0 = (ix0 >= 0 && ix0 < 64) ? 1.f : 0.f;
                float bx1 = (ix1 >= 0 && ix1 < 64) ? 1.f : 0.f;
                float by0 = (iy0 >= 0 && iy0 < 64) ? 1.f : 0.f;
                float by1 = (iy1 >= 0 && iy1 < 64) ? 1.f : 0.f;
                int cx0 = min(max(ix0, 0), 63), cx1 = min(max(ix1, 0), 63);
                int cy0 = min(max(iy0, 0), 63), cy1 = min(max(iy1, 0), 63);
                const unsigned short* fb = featbf + ((long)(b * 8 + c) << 20);
                const uint2* r00 = (const uint2*)(fb + ((cy0 * 64 + cx0) << 8)) + lane;
                const uint2* r01 = (const uint2*)(fb + ((cy0 * 64 + cx1) << 8)) + lane;
                const uint2* r10 = (const uint2*)(fb + ((cy1 * 64 + cx0) << 8)) + lane;
                const uint2* r11 = (const uint2*)(fb + ((cy1 * 64 + cx1) << 8)) + lane;
                float w00 = (1.f - wy) * (1.f - wx) * by0 * bx0;
                float w01 = (1.f - wy) * wx * by0 * bx1;
                float w10 = wy * (1.f - wx) * by1 * bx0;
                float w11 = wy * wx * by1 * bx1;
                uint2 v00 = *r00, v01 = *r01, v10 = *r10, v11 = *r11;
                float4 s;
                s.x = w00 * bf_lo(v00.x) + w01 * bf_lo(v01.x) + w10 * bf_lo(v10.x) + w11 * bf_lo(v11.x);
                s.y = w00 * bf_hi(v00.x) + w01 * bf_hi(v01.x) + w10 * bf_hi(v10.x) + w11 * bf_hi(v11.x);
                s.z = w00 * bf_lo(v00.y) + w01 * bf_lo(v01.y) + w10 * bf_lo(v10.y) + w11 * bf_lo(v11.y);
                s.w = w00 * bf_hi(v00.y) + w01 * bf_hi(v01.y) + w10 * bf_hi(v10.y) + w11 * bf_hi(v11.y);
                float t = s.x * p4.x + s.y * p4.y + s.z * p4.z + s.w * p4.w;
                t += __shfl_xor(t, 32); t += __shfl_xor(t, 16); t += __shfl_xor(t, 8);
                t += __shfl_xor(t, 4);  t += __shfl_xor(t, 2);  t += __shfl_xor(t, 1);
                t *= 0.0625f;
                float nm = fmaxf(m, t);
                float scale = __expf(m - nm);     // m=-inf -> 0 on first valid ctx
                float w = __expf(t - nm);
                ssum = ssum * scale + w;
                sbacc.x = fmaf(w, s.x, sbacc.x * scale);
                sbacc.y = fmaf(w, s.y, sbacc.y * scale);
                sbacc.z = fmaf(w, s.z, sbacc.z * scale);
                sbacc.w = fmaf(w, s.w, sbacc.w * scale);
                m = nm;
            }
        }

        float4 sb = {0.f, 0.f, 0.f, 0.f};
        float sa = 0.f;
        if (m > -INFINITY) {        // wave-uniform
            float inv = 1.f / ssum;
            sb.x = sbacc.x * inv;
            sb.y = sbacc.y * inv;
            sb.z = sbacc.z * inv;
            sb.w = sbacc.w * inv;
            sa = 1.f;
        }
        // sbar bf16 overlays this row's p storage (safe: values data-depend on p4 reads)
        unsigned lo = (unsigned)f2bf(sb.x) | ((unsigned)f2bf(sb.y) << 16);
        unsigned hi = (unsigned)f2bf(sb.z) | ((unsigned)f2bf(sb.w) << 16);
        *(uint2*)((unsigned short*)&buf[r * SLOT] + 4 * lane) = make_uint2(lo, hi);
        if (lane == 0) ssu[r] = sa;
    }
    __syncthreads();

    // ---------------- phase 4: out-GEMM: sbar @ Wvo^T  (MFMA) ----------------
    {
        f32x4 acc2[2][2];
        #pragma unroll
        for (int mt = 0; mt < 2; ++mt)
            #pragma unroll
            for (int nt = 0; nt < 2; ++nt) acc2[mt][nt] = zero;

        #pragma unroll
        for (int ks = 0; ks < 8; ++ks) {
            short8 bfr[2], afr[2];
            #pragma unroll
            for (int nt = 0; nt < 2; ++nt)
                bfr[nt] = *(const short8*)(Wvobf + ((wave * 32 + nt * 16 + r16) << 8) + ks * 32 + g * 8);
            #pragma unroll
            for (int mt = 0; mt < 2; ++mt)
                afr[mt] = *(const short8*)((const unsigned short*)buf + (mt * 16 + r16) * (SLOT * 2) + ks * 32 + g * 8);
            #pragma unroll
            for (int mt = 0; mt < 2; ++mt)
                #pragma unroll
                for (int nt = 0; nt < 2; ++nt)
                    acc2[mt][nt] = __builtin_amdgcn_mfma_f32_16x16x32_bf16(afr[mt], bfr[nt], acc2[mt][nt], 0, 0, 0);
        }
        __syncthreads();   // all sbar reads complete before overwriting slab with out tile

        #pragma unroll
        for (int mt = 0; mt < 2; ++mt)
            #pragma unroll
            for (int nt = 0; nt < 2; ++nt)
                #pragma unroll
                for (int rg = 0; rg < 4; ++rg)
                    buf[(mt * 16 + g * 4 + rg) * SLOT + wave * 32 + nt * 16 + r16] = acc2[mt][nt][rg];
    }
    __syncthreads();

    // ---------------- phase 5: out = residual + tile + suma*bvo + bo  (float4 stores) --
    {
        float4 bvo4 = *(const float4*)(bvo + 4 * lane);
        float4 bo4  = *(const float4*)(bo + 4 * lane);
        #pragma unroll
        for (int rr = 0; rr < 4; ++rr) {
            int r = wave * 4 + rr;
            float4 q4 = qstash[rr];
            float4 a4 = *(const float4*)(&buf[r * SLOT + 4 * lane]);
            float su = ssu[r];
            float4 o;
            o.x = q4.x + a4.x + su * bvo4.x + bo4.x;
            o.y = q4.y + a4.y + su * bvo4.y + bo4.y;
            o.z = q4.z + a4.z + su * bvo4.z + bo4.z;
            o.w = q4.w + a4.w + su * bvo4.w + bo4.w;
            *(float4*)(out + (row0 + r) * 256 + 4 * lane) = o;
        }
    }
}

extern "C" void kernel_launch(void* const* d_in, const int* in_sizes, int n_in,
                              void* d_out, int out_size, void* d_ws, size_t ws_size,
                              hipStream_t stream) {
    const float* queries = (const float*)d_in[0];
    const float* feat    = (const float*)d_in[1];
    const float* coords  = (const float*)d_in[2];
    const int*   vmask   = (const int*)  d_in[3];
    const float* Wq      = (const float*)d_in[4];
    const float* bq      = (const float*)d_in[5];
    const float* Wkv     = (const float*)d_in[6];
    const float* bkv     = (const float*)d_in[7];
    const float* Wo      = (const float*)d_in[8];
    const float* bo      = (const float*)d_in[9];
    const float* gamma   = (const float*)d_in[10];
    const float* beta    = (const float*)d_in[11];
    float* out = (float*)d_out;
    float* ws  = (float*)d_ws;

    precompute_kernel<<<514 + 4096, 256, 0, stream>>>(Wq, bq, Wkv, bkv, Wo, feat, ws);
    fused_rowpipe<<<NROWS / RPB, 512, 0, stream>>>(queries, gamma, beta, coords, vmask, bo, ws, out);
}